// Round 4
// baseline (278.483 us; speedup 1.0000x reference)
//
#include <hip/hip_runtime.h>

// QuantLinearFP8: out[m,n] = sum_k x[m,k] * w[n,k] * scale[n, k/128] + bias[n]
// M=64, K=4096, N=11008, G=128.
//
// R4: barrier-free K-loop. x chunk staged to LDS ONCE per block (bf16,
// A-frag-major [kg][m][8] -> ds_read_b128, bank-balanced), single barrier.
// Then the k-loop streams w global->reg in B-frag layout (w is single-use)
// with a depth-2 rotating prefetch, 4 MFMA per 32-k step, NO __syncthreads
// -> no forced vmcnt(0) drains, loads stay in flight across steps.
// KSPLIT=16 -> 2752 blocks, 32.5KB LDS, 4 blocks/CU (16 waves/CU).
// Pass 2 reduces 16 partials + bias (deterministic, overwrites poison).

#define Md 64
#define Kd 4096
#define Nd 11008
#define NGROUPS 32
#define BN 64
#define KSPLIT 16
#define KCHUNK (Kd / KSPLIT)     // 256
#define NSTEP (KCHUNK / 32)      // 8 k-steps
#define NGRP (KCHUNK / 128)      // 2 scale groups per chunk
#define KGS 64                   // kg-row stride in elements of 8 (m count)

typedef __attribute__((ext_vector_type(8))) __bf16 bf16x8;
typedef __attribute__((ext_vector_type(4))) float f32x4;

__global__ __launch_bounds__(256, 4)
void qlinear_pass1(const float* __restrict__ x,
                   const float* __restrict__ w,
                   const float* __restrict__ scale,
                   float* __restrict__ ws)
{
    const int tid  = threadIdx.x;
    const int wv   = tid >> 6;
    const int lane = tid & 63;
    const int quad = lane >> 4;
    const int ln   = lane & 15;

    const int n0 = blockIdx.x * BN;
    const int ky = blockIdx.y;
    const int k0 = ky * KCHUNK;

    // ---- one-time x staging: f32 -> bf16, A-frag-major [kg][m][8] ----
    // kg = k-octet index (8 consecutive k), so an A-frag for (t, step) is
    // one contiguous 16B at ((step*4+quad)*64 + t*16+ln)*8 elements.
    __shared__ __bf16 lds_x[(KCHUNK / 8) * 64 * 8];   // 32*64*8*2B = 32 KB

    {
        const int m = tid >> 2;          // 0..63
        const int q = tid & 3;
        const float* xp = x + (size_t)m * Kd + k0;
        #pragma unroll
        for (int j = 0; j < 4; ++j) {
            const int c = q * 16 + j * 64;        // float col offset in chunk
            float4 a = *(const float4*)(xp + c);
            float4 b = *(const float4*)(xp + c + 4);
            float4 e = *(const float4*)(xp + c + 8);
            float4 d = *(const float4*)(xp + c + 12);
            bf16x8 v0 = {(__bf16)a.x, (__bf16)a.y, (__bf16)a.z, (__bf16)a.w,
                         (__bf16)b.x, (__bf16)b.y, (__bf16)b.z, (__bf16)b.w};
            bf16x8 v1 = {(__bf16)e.x, (__bf16)e.y, (__bf16)e.z, (__bf16)e.w,
                         (__bf16)d.x, (__bf16)d.y, (__bf16)d.z, (__bf16)d.w};
            const int kg = c >> 3;
            *(bf16x8*)&lds_x[(size_t)(kg * KGS + m) * 8]       = v0;
            *(bf16x8*)&lds_x[(size_t)((kg + 1) * KGS + m) * 8] = v1;
        }
    }
    __syncthreads();   // the ONLY barrier

    // ---- barrier-free k-loop: stream w, MFMA ----
    const int nrow = n0 + wv * 16 + ln;
    const float* wp = w + (size_t)nrow * Kd + k0 + quad * 8;

    // 2 group scales for this chunk
    const float2 sc2 = *(const float2*)(scale + (size_t)nrow * NGROUPS
                                        + ky * NGRP);
    const float sc[2] = {sc2.x, sc2.y};

    f32x4 acc[4];
    #pragma unroll
    for (int t = 0; t < 4; ++t) acc[t] = (f32x4){0.f, 0.f, 0.f, 0.f};

    // depth-2 rotating w prefetch (3 slots x 2 float4)
    float4 wb[3][2];
    wb[0][0] = *(const float4*)(wp + 0);
    wb[0][1] = *(const float4*)(wp + 4);
    wb[1][0] = *(const float4*)(wp + 32);
    wb[1][1] = *(const float4*)(wp + 36);

    #pragma unroll
    for (int g = 0; g < NGRP; ++g) {
        f32x4 pg[4];
        #pragma unroll
        for (int t = 0; t < 4; ++t) pg[t] = (f32x4){0.f, 0.f, 0.f, 0.f};

        #pragma unroll
        for (int ks = 0; ks < 4; ++ks) {
            const int step = g * 4 + ks;
            if (step + 2 < NSTEP) {
                const int s = step + 2;
                wb[s % 3][0] = *(const float4*)(wp + s * 32);
                wb[s % 3][1] = *(const float4*)(wp + s * 32 + 4);
            }
            float4 wa = wb[step % 3][0], wbv = wb[step % 3][1];
            bf16x8 wf = {(__bf16)wa.x,  (__bf16)wa.y,  (__bf16)wa.z,  (__bf16)wa.w,
                         (__bf16)wbv.x, (__bf16)wbv.y, (__bf16)wbv.z, (__bf16)wbv.w};
            #pragma unroll
            for (int t = 0; t < 4; ++t) {
                bf16x8 xf = *(const bf16x8*)
                    &lds_x[(size_t)((step * 4 + quad) * KGS + t * 16 + ln) * 8];
                pg[t] = __builtin_amdgcn_mfma_f32_16x16x32_bf16(xf, wf, pg[t],
                                                                0, 0, 0);
            }
        }

        const float s = sc[g];
        #pragma unroll
        for (int t = 0; t < 4; ++t)
            #pragma unroll
            for (int r = 0; r < 4; ++r)
                acc[t][r] += s * pg[t][r];
    }

    // partials -> ws[ky][m][n]  (C/D: m = t*16 + quad*4 + r, col = ln)
    float* op = ws + ((size_t)ky * Md) * Nd + n0 + wv * 16 + ln;
    #pragma unroll
    for (int t = 0; t < 4; ++t)
        #pragma unroll
        for (int r = 0; r < 4; ++r)
            op[(size_t)(t * 16 + quad * 4 + r) * Nd] = acc[t][r];
}

__global__ __launch_bounds__(256)
void qlinear_reduce(const float* __restrict__ ws,
                    const float* __restrict__ bias,
                    float* __restrict__ out)
{
    const int idx4 = blockIdx.x * 256 + threadIdx.x;   // float4 index
    if (idx4 >= Md * Nd / 4) return;
    const int n4 = idx4 % (Nd / 4);
    float4 v = *(const float4*)(bias + n4 * 4);
    #pragma unroll
    for (int ky = 0; ky < KSPLIT; ++ky) {
        float4 p = *(const float4*)(ws + (size_t)ky * Md * Nd + (size_t)idx4 * 4);
        v.x += p.x; v.y += p.y; v.z += p.z; v.w += p.w;
    }
    *(float4*)(out + (size_t)idx4 * 4) = v;
}

extern "C" void kernel_launch(void* const* d_in, const int* in_sizes, int n_in,
                              void* d_out, int out_size, void* d_ws, size_t ws_size,
                              hipStream_t stream) {
    const float* x     = (const float*)d_in[0];  // [64][4096]
    const float* w     = (const float*)d_in[1];  // [11008][4096]
    const float* scale = (const float*)d_in[2];  // [11008][32]
    const float* bias  = (const float*)d_in[3];  // [11008]
    float* out = (float*)d_out;                  // [64][11008] f32
    float* ws  = (float*)d_ws;                   // [16][64][11008] f32 = 45 MB

    dim3 grid1(Nd / BN, KSPLIT);
    qlinear_pass1<<<grid1, 256, 0, stream>>>(x, w, scale, ws);

    const int total4 = Md * Nd / 4;              // 176128 = 688 * 256
    qlinear_reduce<<<(total4 + 255) / 256, 256, 0, stream>>>(ws, bias, out);
}